// Round 1
// baseline (1755.204 us; speedup 1.0000x reference)
//
#include <hip/hip_runtime.h>

#define EPS_LN 1e-8f

__device__ __forceinline__ float sigmoidf_(float x){ return 1.0f/(1.0f+__expf(-x)); }
__device__ __forceinline__ float siluf_(float x){ return x*sigmoidf_(x); }

union F4 { float4 v; float f[4]; };

// ---------------- Kernel A: node separable layernorm (one wave per node) ----------------
__global__ void node_ln_kernel(const float* __restrict__ nf,
                               const float* __restrict__ ws, const float* __restrict__ bs,
                               const float* __restrict__ wv,
                               float* __restrict__ ns, float* __restrict__ nv, int N)
{
    int t = threadIdx.x;
    int lane = t & 63;
    int n = blockIdx.x*4 + (t>>6);
    if (n >= N) return;
    const float* row = nf + (size_t)n*320;
    float s0 = row[lane], s1 = row[64+lane];
    float sum = s0+s1, sq = s0*s0+s1*s1;
    #pragma unroll
    for (int m=1;m<64;m<<=1){ sum += __shfl_xor(sum,m,64); sq += __shfl_xor(sq,m,64); }
    float mu = sum*(1.0f/128.0f);
    float rs = rsqrtf(sq*(1.0f/128.0f) - mu*mu + EPS_LN);
    ns[(size_t)n*128+lane]    = (s0-mu)*rs*ws[lane]    + bs[lane];
    ns[(size_t)n*128+64+lane] = (s1-mu)*rs*ws[64+lane] + bs[64+lane];
    float v0 = row[128+lane], v1 = row[192+lane], v2 = row[256+lane];
    float vs = v0*v0+v1*v1+v2*v2;
    #pragma unroll
    for (int m=1;m<64;m<<=1) vs += __shfl_xor(vs,m,64);
    float rv = rsqrtf(vs*(1.0f/192.0f) + EPS_LN);
    nv[(size_t)n*192+lane]     = v0*rv*wv[lane/3];
    nv[(size_t)n*192+64+lane]  = v1*rv*wv[(64+lane)/3];
    nv[(size_t)n*192+128+lane] = v2*rv*wv[(128+lane)/3];
}

// ---------------- Kernel B: fused edge kernel ----------------
// 16 edges per block, 256 threads. Staging groups: g = t>>4 (edge), l = t&15.
__launch_bounds__(256, 2)
__global__ void edge_kernel(
    const float* __restrict__ latents,
    const float* __restrict__ ef_all,
    const int*   __restrict__ edge_index,
    const float* __restrict__ edge_vector,
    const int*   __restrict__ active_edges,
    const float* __restrict__ e_ws, const float* __restrict__ e_bs, const float* __restrict__ e_wv,
    const float* __restrict__ so2_w0,
    const float* __restrict__ w1r, const float* __restrict__ w1i,
    const float* __restrict__ env_w,
    const float* __restrict__ lp_ws, const float* __restrict__ lp_bs, const float* __restrict__ lp_wv,
    const float* __restrict__ ns, const float* __restrict__ nv,
    float* __restrict__ agg_s, float* __restrict__ agg_v,
    int EA, int EF)
{
    __shared__ __align__(16) float sA[16*588];      // m0_in tile [16][588] (576 used)
    __shared__ __align__(16) float sVF[2*16*196];   // vf1 / vf2 tiles [2][16][196] (192 used)
    __shared__ __align__(16) float sO[16*260];      // m0_out tile [16][260] (256 used)

    const int t = threadIdx.x;
    const int g = t >> 4, l = t & 15;
    const int e = blockIdx.x*16 + g;
    const bool act = (e < EA);

    int ct = 0, ae = 0;
    float ax=0,ay=0,az=0,bx=0,by=0,bz=0,cx=0,cy=0,cz=0;

    // ---- staging phase ----
    if (act) {
        ae = active_edges[e];
        ct = edge_index[ae];
        int nb = edge_index[EF + ae];
        // frame from edge_vector
        float ex = edge_vector[(size_t)ae*3+0];
        float ey = edge_vector[(size_t)ae*3+1];
        float ez = edge_vector[(size_t)ae*3+2];
        float rn = rsqrtf(ex*ex+ey*ey+ez*ez + EPS_LN);
        ax = ex*rn; ay = ey*rn; az = ez*rn;
        float rx, ry;
        if (fabsf(ax) < 0.9f) { rx = 1.0f; ry = 0.0f; } else { rx = 0.0f; ry = 1.0f; }
        bx = -az*ry;           // a x ref, ref=(rx,ry,0)
        by =  az*rx;
        bz =  ax*ry - ay*rx;
        float bn = rsqrtf(bx*bx+by*by+bz*bz + EPS_LN);
        bx*=bn; by*=bn; bz*=bn;
        cx = ay*bz - az*by;
        cy = az*bx - ax*bz;
        cz = ax*by - ay*bx;

        float* Arow = &sA[g*588];
        {   // gather layernormed node scalars
            const float4* pc4 = (const float4*)(ns + (size_t)ct*128);
            const float4* pn4 = (const float4*)(ns + (size_t)nb*128);
            *(float4*)&Arow[l*4]       = pc4[l];
            *(float4*)&Arow[64 + l*4]  = pc4[16+l];
            *(float4*)&Arow[256 + l*4] = pn4[l];
            *(float4*)&Arow[320 + l*4] = pn4[16+l];
        }
        const float* ef = ef_all + (size_t)e*320;
        {   // edge scalar LN
            F4 sa, sb;
            sa.v = *(const float4*)(ef + l*4);
            sb.v = *(const float4*)(ef + 64 + l*4);
            float sum=0.f, sq=0.f;
            #pragma unroll
            for (int i=0;i<4;i++){ sum += sa.f[i]+sb.f[i]; sq += sa.f[i]*sa.f[i]+sb.f[i]*sb.f[i]; }
            #pragma unroll
            for (int m=1;m<16;m<<=1){ sum += __shfl_xor(sum,m,64); sq += __shfl_xor(sq,m,64); }
            float mu = sum*(1.0f/128.0f);
            float rs = rsqrtf(sq*(1.0f/128.0f)-mu*mu + EPS_LN);
            #pragma unroll
            for (int i=0;i<4;i++){
                int c0 = l*4+i, c1 = 64+l*4+i;
                Arow[128+c0] = (sa.f[i]-mu)*rs*e_ws[c0]+e_bs[c0];
                Arow[128+c1] = (sb.f[i]-mu)*rs*e_ws[c1]+e_bs[c1];
            }
        }
        {   // edge vector LN + rotate (u block 64..127)
            F4 va, vb, vc;
            va.v = *(const float4*)(ef + 128 + l*12);
            vb.v = *(const float4*)(ef + 128 + l*12 + 4);
            vc.v = *(const float4*)(ef + 128 + l*12 + 8);
            float vv[12];
            #pragma unroll
            for (int i=0;i<4;i++){ vv[i]=va.f[i]; vv[4+i]=vb.f[i]; vv[8+i]=vc.f[i]; }
            float sq=0.f;
            #pragma unroll
            for (int i=0;i<12;i++) sq += vv[i]*vv[i];
            #pragma unroll
            for (int m=1;m<16;m<<=1) sq += __shfl_xor(sq,m,64);
            float rv = rsqrtf(sq*(1.0f/192.0f) + EPS_LN);
            #pragma unroll
            for (int j=0;j<4;j++){
                int u = 4*l + j;
                float sc = rv * e_wv[u];
                float x = vv[3*j]*sc, y = vv[3*j+1]*sc, z = vv[3*j+2]*sc;
                Arow[384+64+u]           = ax*x+ay*y+az*z;
                sVF[g*196 + 64+u]        = bx*x+by*y+bz*z;
                sVF[3136 + g*196 + 64+u] = cx*x+cy*y+cz*z;
            }
        }
        {   // nv[ctr] gather + rotate (u block 0..63)
            const float* pv = nv + (size_t)ct*192 + l*12;
            F4 va, vb, vc;
            va.v = *(const float4*)(pv);
            vb.v = *(const float4*)(pv+4);
            vc.v = *(const float4*)(pv+8);
            float vv[12];
            #pragma unroll
            for (int i=0;i<4;i++){ vv[i]=va.f[i]; vv[4+i]=vb.f[i]; vv[8+i]=vc.f[i]; }
            #pragma unroll
            for (int j=0;j<4;j++){
                int u = 4*l+j;
                float x = vv[3*j], y = vv[3*j+1], z = vv[3*j+2];
                Arow[384+u]           = ax*x+ay*y+az*z;
                sVF[g*196 + u]        = bx*x+by*y+bz*z;
                sVF[3136 + g*196 + u] = cx*x+cy*y+cz*z;
            }
        }
        {   // nv[nbr] gather + rotate (u block 128..191)
            const float* pv = nv + (size_t)edge_index[EF+ae]*192 + l*12;
            F4 va, vb, vc;
            va.v = *(const float4*)(pv);
            vb.v = *(const float4*)(pv+4);
            vc.v = *(const float4*)(pv+8);
            float vv[12];
            #pragma unroll
            for (int i=0;i<4;i++){ vv[i]=va.f[i]; vv[4+i]=vb.f[i]; vv[8+i]=vc.f[i]; }
            #pragma unroll
            for (int j=0;j<4;j++){
                int u = 4*l+j;
                float x = vv[3*j], y = vv[3*j+1], z = vv[3*j+2];
                Arow[384+128+u]           = ax*x+ay*y+az*z;
                sVF[g*196 + 128+u]        = bx*x+by*y+bz*z;
                sVF[3136 + g*196 + 128+u] = cx*x+cy*y+cz*z;
            }
        }
    }
    __syncthreads();

    // ---- main GEMM: m0_out[16][256] = A[16][576] @ so2_w0[576][256] ----
    {
        const int er = t >> 6;              // wave id -> edge sub-block (4 edges)
        const int col0 = (t & 63)*4;
        float acc[4][4];
        #pragma unroll
        for (int i=0;i<4;i++)
            #pragma unroll
            for (int j=0;j<4;j++) acc[i][j]=0.f;
        const float* A0 = &sA[(er*4+0)*588];
        const float* A1 = &sA[(er*4+1)*588];
        const float* A2 = &sA[(er*4+2)*588];
        const float* A3 = &sA[(er*4+3)*588];
        const float* Wp = so2_w0 + col0;
        for (int k=0;k<576;k+=4){
            F4 a0,a1,a2,a3;
            a0.v = *(const float4*)(A0+k);
            a1.v = *(const float4*)(A1+k);
            a2.v = *(const float4*)(A2+k);
            a3.v = *(const float4*)(A3+k);
            F4 w0,w1_,w2,w3;
            w0.v  = *(const float4*)(Wp + (size_t)(k+0)*256);
            w1_.v = *(const float4*)(Wp + (size_t)(k+1)*256);
            w2.v  = *(const float4*)(Wp + (size_t)(k+2)*256);
            w3.v  = *(const float4*)(Wp + (size_t)(k+3)*256);
            const float* wrow[4] = { w0.f, w1_.f, w2.f, w3.f };
            const float* arow0[4] = { a0.f, a1.f, a2.f, a3.f };
            #pragma unroll
            for (int kk=0;kk<4;kk++){
                #pragma unroll
                for (int ee=0;ee<4;ee++){
                    float av = arow0[ee][kk];
                    #pragma unroll
                    for (int cc2=0;cc2<4;cc2++)
                        acc[ee][cc2] += av * wrow[kk][cc2];
                }
            }
        }
        const float rn0 = 0.0416666666667f;   // 1/sqrt(576)
        #pragma unroll
        for (int ee=0;ee<4;ee++){
            int eg = er*4+ee;
            if (blockIdx.x*16 + eg < EA) {
                float4 o;
                o.x = acc[ee][0]*rn0; o.y = acc[ee][1]*rn0;
                o.z = acc[ee][2]*rn0; o.w = acc[ee][3]*rn0;
                *(float4*)&sO[eg*260 + col0] = o;
            }
        }
    }
    __syncthreads();

    // ---- epilogue scratch overlaid on sA (A-tile fully consumed) ----
    float* MS0 = sA;            // [16][132] silu'd scalars
    float* MV  = sA + 2112;     // [16][260] gated rotated vectors ([64][4] per edge)
    float* WE  = sA + 6272;     // [16][196] env weights (192 used)

    // ---- E1: vp/vm GEMMs, silu, gate+inverse-rotate, env linear ----
    if (act) {
        const int j0 = l*4;
        float pr[4] = {0,0,0,0}, qm[4] = {0,0,0,0};
        for (int k=0;k<192;k+=4){
            F4 v1, v2;
            v1.v = *(const float4*)&sVF[g*196 + k];
            v2.v = *(const float4*)&sVF[3136 + g*196 + k];
            #pragma unroll
            for (int kk=0;kk<4;kk++){
                F4 wr, wi;
                wr.v = *(const float4*)(w1r + (size_t)(k+kk)*64 + j0);
                wi.v = *(const float4*)(w1i + (size_t)(k+kk)*64 + j0);
                #pragma unroll
                for (int c=0;c<4;c++){
                    pr[c] += v1.f[kk]*wr.f[c] - v2.f[kk]*wi.f[c];
                    qm[c] += v1.f[kk]*wi.f[c] + v2.f[kk]*wr.f[c];
                }
            }
        }
        const float n1 = 0.0721687836487f;    // 1/sqrt(192)
        #pragma unroll
        for (int c=0;c<4;c++){ pr[c]*=n1; qm[c]*=n1; }

        {   // silu of scalar part -> MS0
            int i0 = l*8;
            F4 oa, ob;
            oa.v = *(const float4*)&sO[g*260 + i0];
            ob.v = *(const float4*)&sO[g*260 + i0 + 4];
            #pragma unroll
            for (int i=0;i<4;i++){
                MS0[g*132 + i0 + i]   = siluf_(oa.f[i]);
                MS0[g*132 + i0+4 + i] = siluf_(ob.f[i]);
            }
        }
        // gate + rotate back (R^T) -> MV
        #pragma unroll
        for (int j=0;j<4;j++){
            int u = j0 + j;
            float s0 = sO[g*260 + 192 + u];
            float gu = sigmoidf_(sO[g*260 + 128 + u]);
            float vx = ax*s0 + bx*pr[j] + cx*qm[j];
            float vy = ay*s0 + by*pr[j] + cy*qm[j];
            float vz = az*s0 + bz*pr[j] + cz*qm[j];
            MV[g*260 + u*4+0] = gu*vx;
            MV[g*260 + u*4+1] = gu*vy;
            MV[g*260 + u*4+2] = gu*vz;
            MV[g*260 + u*4+3] = 0.0f;
        }
        {   // env weights: w = latents[ae] @ env_w / sqrt(128)
            const int cc = l*12;
            float wacc[12];
            #pragma unroll
            for (int i=0;i<12;i++) wacc[i]=0.f;
            const float* lat = latents + (size_t)ae*128;
            for (int k=0;k<128;k+=4){
                F4 la;
                la.v = *(const float4*)(lat + k);
                #pragma unroll
                for (int kk=0;kk<4;kk++){
                    const float* er_ = env_w + (size_t)(k+kk)*192 + cc;
                    F4 e0,e1,e2;
                    e0.v = *(const float4*)(er_);
                    e1.v = *(const float4*)(er_+4);
                    e2.v = *(const float4*)(er_+8);
                    #pragma unroll
                    for (int i=0;i<4;i++){
                        wacc[i]   += la.f[kk]*e0.f[i];
                        wacc[4+i] += la.f[kk]*e1.f[i];
                        wacc[8+i] += la.f[kk]*e2.f[i];
                    }
                }
            }
            const float inv128 = 0.0883883476483f;   // 1/sqrt(128)
            #pragma unroll
            for (int i=0;i<12;i++) WE[g*196 + cc + i] = wacc[i]*inv128;
        }
    }
    __syncthreads();

    // ---- E2: lp linears + env scaling + atomic scatter ----
    if (act) {
        const float inv_avg = 0.288675134595f;   // 1/sqrt(12)
        {   // scalar path: ms1 = silu(ms)@lp_ws/sqrt(128) + lp_bs, * w, scatter
            int c0 = l*8;
            float a8[8];
            #pragma unroll
            for (int i=0;i<8;i++) a8[i]=0.f;
            for (int k=0;k<128;k+=4){
                F4 av;
                av.v = *(const float4*)&MS0[g*132 + k];
                #pragma unroll
                for (int kk=0;kk<4;kk++){
                    const float* wr = lp_ws + (size_t)(k+kk)*128 + c0;
                    F4 w0, w1_;
                    w0.v  = *(const float4*)(wr);
                    w1_.v = *(const float4*)(wr+4);
                    #pragma unroll
                    for (int i=0;i<4;i++){ a8[i] += av.f[kk]*w0.f[i]; a8[4+i] += av.f[kk]*w1_.f[i]; }
                }
            }
            const float s128 = 0.0883883476483f;
            #pragma unroll
            for (int i=0;i<8;i++){
                int c = c0+i;
                float val = (a8[i]*s128 + lp_bs[c]) * WE[g*196 + c] * inv_avg;
                atomicAdd(&agg_s[(size_t)ct*128 + c], val);
            }
        }
        {   // vector path: mv1[k][m] = sum_u mv[u][m]*lp_wv[u][k]/8, * w, scatter
            int k0 = l*4;
            float av[4][3];
            #pragma unroll
            for (int j=0;j<4;j++)
                #pragma unroll
                for (int m2=0;m2<3;m2++) av[j][m2]=0.f;
            for (int u=0;u<64;u++){
                F4 wv4, mv4;
                wv4.v = *(const float4*)(lp_wv + (size_t)u*64 + k0);
                mv4.v = *(const float4*)&MV[g*260 + u*4];
                #pragma unroll
                for (int j=0;j<4;j++){
                    av[j][0] += wv4.f[j]*mv4.f[0];
                    av[j][1] += wv4.f[j]*mv4.f[1];
                    av[j][2] += wv4.f[j]*mv4.f[2];
                }
            }
            #pragma unroll
            for (int j=0;j<4;j++){
                int k = k0+j;
                float wk = WE[g*196 + 128 + k] * 0.125f * inv_avg;
                #pragma unroll
                for (int m2=0;m2<3;m2++)
                    atomicAdd(&agg_v[(size_t)ct*192 + k*3 + m2], av[j][m2]*wk);
            }
        }
    }
}

// ---------------- Kernel C: per-node onehot path + output ----------------
__global__ void node_out_kernel(
    const float* __restrict__ nf,
    const int* __restrict__ atom_type,
    const float* __restrict__ agg_s, const float* __restrict__ agg_v,
    const float* __restrict__ oh_ss, const float* __restrict__ oh_sg, const float* __restrict__ oh_vv,
    const float* __restrict__ ohl_ws, const float* __restrict__ ohl_bs, const float* __restrict__ ohl_wv,
    const float* __restrict__ res_param,
    float* __restrict__ out, int N)
{
    __shared__ float AGS[128];
    __shared__ float AGV[192];
    __shared__ float TSs[128];
    __shared__ float SG[64];
    __shared__ float TV[192];
    const int n = blockIdx.x;
    const int t = threadIdx.x;
    const int at = atom_type[n];
    if (t < 128) AGS[t] = agg_s[(size_t)n*128 + t];
    if (t < 192) AGV[t] = agg_v[(size_t)n*192 + t];
    __syncthreads();
    const float n_ss = 0.0110485434560f;   // 1/sqrt(128*64)
    const float n_vv = 0.015625f;          // 1/sqrt(64*64)
    if (t < 128) {
        float acc = 0.0f;
        for (int u=0;u<128;u++) acc += AGS[u]*oh_ss[(size_t)u*8192 + (size_t)at*128 + t];
        TSs[t] = siluf_(acc*n_ss);
    } else if (t < 192) {
        int k = t-128;
        float acc = 0.0f;
        for (int u=0;u<128;u++) acc += AGS[u]*oh_sg[(size_t)u*4096 + (size_t)at*64 + k];
        SG[k] = sigmoidf_(acc*n_ss);
    } else {
        int k = t-192;
        float a0=0,a1=0,a2=0;
        for (int u=0;u<64;u++){
            float w = oh_vv[(size_t)u*4096 + (size_t)at*64 + k];
            a0 += AGV[u*3+0]*w;
            a1 += AGV[u*3+1]*w;
            a2 += AGV[u*3+2]*w;
        }
        TV[k*3+0]=a0*n_vv; TV[k*3+1]=a1*n_vv; TV[k*3+2]=a2*n_vv;
    }
    __syncthreads();
    const float alpha = sigmoidf_(res_param[0]);
    const float beta  = 1.0f - alpha;
    if (t < 128) {
        float acc = 0.0f;
        for (int k=0;k<128;k++) acc += TSs[k]*ohl_ws[(size_t)k*128 + t];
        float val = acc*0.0883883476483f + ohl_bs[t];
        out[(size_t)n*320 + t] = alpha*nf[(size_t)n*320 + t] + beta*val;
    } else if (t >= 192) {
        int k = t-192;
        float a0=0,a1=0,a2=0;
        for (int u=0;u<64;u++){
            float w = ohl_wv[(size_t)u*64 + k]*SG[u];
            a0 += TV[u*3+0]*w; a1 += TV[u*3+1]*w; a2 += TV[u*3+2]*w;
        }
        size_t base = (size_t)n*320 + 128 + (size_t)k*3;
        out[base+0] = alpha*nf[base+0] + beta*(a0*0.125f);
        out[base+1] = alpha*nf[base+1] + beta*(a1*0.125f);
        out[base+2] = alpha*nf[base+2] + beta*(a2*0.125f);
    }
}

extern "C" void kernel_launch(void* const* d_in, const int* in_sizes, int n_in,
                              void* d_out, int out_size, void* d_ws, size_t ws_size,
                              hipStream_t stream)
{
    const float* latents       = (const float*)d_in[0];
    const float* node_features = (const float*)d_in[1];
    const float* edge_features = (const float*)d_in[2];
    const int*   atom_type     = (const int*)d_in[3];
    // d_in[4] node_onehot unused (atom_type is enough)
    const int*   edge_index    = (const int*)d_in[5];
    const float* edge_vector   = (const float*)d_in[6];
    const int*   active_edges  = (const int*)d_in[7];
    const float* sln_n_ws = (const float*)d_in[8];
    const float* sln_n_bs = (const float*)d_in[9];
    const float* sln_n_wv = (const float*)d_in[10];
    const float* sln_e_ws = (const float*)d_in[11];
    const float* sln_e_bs = (const float*)d_in[12];
    const float* sln_e_wv = (const float*)d_in[13];
    const float* so2_w0   = (const float*)d_in[14];
    const float* so2_w1r  = (const float*)d_in[15];
    const float* so2_w1i  = (const float*)d_in[16];
    const float* env_w    = (const float*)d_in[17];
    const float* lp_ws    = (const float*)d_in[18];
    const float* lp_bs    = (const float*)d_in[19];
    const float* lp_wv    = (const float*)d_in[20];
    const float* oh_w_ss  = (const float*)d_in[21];
    const float* oh_w_sg  = (const float*)d_in[22];
    const float* oh_w_vv  = (const float*)d_in[23];
    const float* ohl_ws   = (const float*)d_in[24];
    const float* ohl_bs   = (const float*)d_in[25];
    const float* ohl_wv   = (const float*)d_in[26];
    const float* res_param= (const float*)d_in[27];
    float* out = (float*)d_out;

    const int N  = in_sizes[1] / 320;
    const int EF = in_sizes[5] / 2;
    const int EA = in_sizes[7];

    float* ns    = (float*)d_ws;
    float* nv    = ns + (size_t)N*128;
    float* agg_s = nv + (size_t)N*192;
    float* agg_v = agg_s + (size_t)N*128;

    hipMemsetAsync(agg_s, 0, (size_t)N*(128+192)*sizeof(float), stream);
    node_ln_kernel<<<(N+3)/4, 256, 0, stream>>>(node_features, sln_n_ws, sln_n_bs, sln_n_wv, ns, nv, N);
    edge_kernel<<<(EA+15)/16, 256, 0, stream>>>(latents, edge_features, edge_index, edge_vector, active_edges,
        sln_e_ws, sln_e_bs, sln_e_wv, so2_w0, so2_w1r, so2_w1i, env_w, lp_ws, lp_bs, lp_wv,
        ns, nv, agg_s, agg_v, EA, EF);
    node_out_kernel<<<N, 256, 0, stream>>>(node_features, atom_type, agg_s, agg_v, oh_w_ss, oh_w_sg, oh_w_vv,
        ohl_ws, ohl_bs, ohl_wv, res_param, out, N);
}

// Round 2
// 1418.989 us; speedup vs baseline: 1.2369x; 1.2369x over previous
//
#include <hip/hip_runtime.h>

#define EPS_LN 1e-8f

typedef __bf16 bf16x8 __attribute__((ext_vector_type(8)));
typedef float  f32x4  __attribute__((ext_vector_type(4)));

__device__ __forceinline__ float sigmoidf_(float x){ return 1.0f/(1.0f+__expf(-x)); }
__device__ __forceinline__ float siluf_(float x){ return x*sigmoidf_(x); }

union F4 { float4 v; float f[4]; };

// swizzled bf16 store of 4 consecutive elements (k multiple of 4)
__device__ __forceinline__ void st_bf4(char* base, int row, int stride_bytes, int k,
                                       float x0, float x1, float x2, float x3){
    union { __bf16 h[4]; unsigned long long u; } p;
    p.h[0]=(__bf16)x0; p.h[1]=(__bf16)x1; p.h[2]=(__bf16)x2; p.h[3]=(__bf16)x3;
    *(unsigned long long*)(base + row*stride_bytes + ((2*k) ^ ((row&7)<<4))) = p.u;
}
// swizzled 16B fragment load (kbyte multiple of 16)
__device__ __forceinline__ bf16x8 ld_frag(const char* base, int row, int stride_bytes, int kbyte){
    return *(const bf16x8*)(base + row*stride_bytes + (kbyte ^ ((row&7)<<4)));
}

// ---------------- weight prep: transpose + f32->bf16 ----------------
__global__ void prep_weights(const float* __restrict__ w0,
                             const float* __restrict__ w1r, const float* __restrict__ w1i,
                             __bf16* __restrict__ Wt, __bf16* __restrict__ w1rt, __bf16* __restrict__ w1it)
{
    int t = blockIdx.x*256 + threadIdx.x;
    if (t < 576*256){
        int c = t/576, k = t%576;
        Wt[t] = (__bf16)w0[(size_t)k*256 + c];
    }
    if (t < 64*192){
        int c = t/192, k = t%192;
        w1rt[t] = (__bf16)w1r[(size_t)k*64 + c];
        w1it[t] = (__bf16)w1i[(size_t)k*64 + c];
    }
}

// ---------------- Kernel A: node separable layernorm (one wave per node) ----------------
__global__ void node_ln_kernel(const float* __restrict__ nf,
                               const float* __restrict__ ws, const float* __restrict__ bs,
                               const float* __restrict__ wv,
                               float* __restrict__ ns, float* __restrict__ nv, int N)
{
    int t = threadIdx.x;
    int lane = t & 63;
    int n = blockIdx.x*4 + (t>>6);
    if (n >= N) return;
    const float* row = nf + (size_t)n*320;
    float s0 = row[lane], s1 = row[64+lane];
    float sum = s0+s1, sq = s0*s0+s1*s1;
    #pragma unroll
    for (int m=1;m<64;m<<=1){ sum += __shfl_xor(sum,m,64); sq += __shfl_xor(sq,m,64); }
    float mu = sum*(1.0f/128.0f);
    float rs = rsqrtf(sq*(1.0f/128.0f) - mu*mu + EPS_LN);
    ns[(size_t)n*128+lane]    = (s0-mu)*rs*ws[lane]    + bs[lane];
    ns[(size_t)n*128+64+lane] = (s1-mu)*rs*ws[64+lane] + bs[64+lane];
    float v0 = row[128+lane], v1 = row[192+lane], v2 = row[256+lane];
    float vs = v0*v0+v1*v1+v2*v2;
    #pragma unroll
    for (int m=1;m<64;m<<=1) vs += __shfl_xor(vs,m,64);
    float rv = rsqrtf(vs*(1.0f/192.0f) + EPS_LN);
    nv[(size_t)n*192+lane]     = v0*rv*wv[lane/3];
    nv[(size_t)n*192+64+lane]  = v1*rv*wv[(64+lane)/3];
    nv[(size_t)n*192+128+lane] = v2*rv*wv[(128+lane)/3];
}

// ---------------- Kernel B: fused edge kernel (MFMA main + vp/vm GEMMs) ----------------
// 16 edges/block, 256 threads (4 waves). LDS phases:
//   phase A: sAb bf16 [16][576] swizzled (stride 1152B), sVF bf16 2x[16][192] (stride 384B)
//   phase B (overlaid): sO f32 [16][260], MV f32 [16][260], WE f32 [16][196]; sR dedicated.
__launch_bounds__(256, 3)
__global__ void edge_kernel(
    const float* __restrict__ latents,
    const float* __restrict__ ef_all,
    const int*   __restrict__ edge_index,
    const float* __restrict__ edge_vector,
    const int*   __restrict__ active_edges,
    const float* __restrict__ e_ws, const float* __restrict__ e_bs, const float* __restrict__ e_wv,
    const __bf16* __restrict__ Wt,      // [256][576] bf16 (transposed so2_w0)
    const __bf16* __restrict__ w1rt,    // [64][192]
    const __bf16* __restrict__ w1it,    // [64][192]
    const float* __restrict__ env_w,
    const float* __restrict__ lp_ws, const float* __restrict__ lp_bs, const float* __restrict__ lp_wv,
    const float* __restrict__ ns, const float* __restrict__ nv,
    float* __restrict__ agg_s, float* __restrict__ agg_v,
    int EA, int EF)
{
    __shared__ __align__(16) char smem[46592];
    char* sAbC = smem;                    // 16*1152 = 18432
    char* sVFC = smem + 18432;            // 2*16*384 = 12288 (ends 30720)
    float* sO  = (float*)smem;            // 16*260*4 = 16640
    float* MV  = (float*)(smem + 16640);  // 16*260*4 = 16640 (ends 33280)
    float* WE  = (float*)(smem + 33280);  // 16*196*4 = 12544 (ends 45824)
    float* sR  = (float*)(smem + 45824);  // 16*12*4  = 768   (ends 46592)

    const int t = threadIdx.x;
    const int g = t >> 4, l = t & 15;
    const int e = blockIdx.x*16 + g;
    const bool act = (e < EA);

    int ct = 0, ae = 0;

    // ---- staging phase ----
    if (act) {
        ae = active_edges[e];
        ct = edge_index[ae];
        int nb = edge_index[EF + ae];
        // frame from edge_vector
        float ex = edge_vector[(size_t)ae*3+0];
        float ey = edge_vector[(size_t)ae*3+1];
        float ez = edge_vector[(size_t)ae*3+2];
        float rn = rsqrtf(ex*ex+ey*ey+ez*ez + EPS_LN);
        float ax = ex*rn, ay = ey*rn, az = ez*rn;
        float rx, ry;
        if (fabsf(ax) < 0.9f) { rx = 1.0f; ry = 0.0f; } else { rx = 0.0f; ry = 1.0f; }
        float bx = -az*ry, by = az*rx, bz = ax*ry - ay*rx;
        float bn = rsqrtf(bx*bx+by*by+bz*bz + EPS_LN);
        bx*=bn; by*=bn; bz*=bn;
        float cx = ay*bz - az*by;
        float cy = az*bx - ax*bz;
        float cz = ax*by - ay*bx;
        if (l == 0){
            float* Rr = &sR[g*12];
            Rr[0]=ax; Rr[1]=ay; Rr[2]=az;
            Rr[3]=bx; Rr[4]=by; Rr[5]=bz;
            Rr[6]=cx; Rr[7]=cy; Rr[8]=cz;
        }

        {   // gather layernormed node scalars -> bf16 A tile
            const float4* pc4 = (const float4*)(ns + (size_t)ct*128);
            const float4* pn4 = (const float4*)(ns + (size_t)nb*128);
            F4 a,b2,c,d;
            a.v = pc4[l]; b2.v = pc4[16+l]; c.v = pn4[l]; d.v = pn4[16+l];
            st_bf4(sAbC, g, 1152, l*4,       a.f[0],a.f[1],a.f[2],a.f[3]);
            st_bf4(sAbC, g, 1152, 64+l*4,    b2.f[0],b2.f[1],b2.f[2],b2.f[3]);
            st_bf4(sAbC, g, 1152, 256+l*4,   c.f[0],c.f[1],c.f[2],c.f[3]);
            st_bf4(sAbC, g, 1152, 320+l*4,   d.f[0],d.f[1],d.f[2],d.f[3]);
        }
        const float* ef = ef_all + (size_t)e*320;
        {   // edge scalar LN
            F4 sa, sb;
            sa.v = *(const float4*)(ef + l*4);
            sb.v = *(const float4*)(ef + 64 + l*4);
            float sum=0.f, sq=0.f;
            #pragma unroll
            for (int i=0;i<4;i++){ sum += sa.f[i]+sb.f[i]; sq += sa.f[i]*sa.f[i]+sb.f[i]*sb.f[i]; }
            #pragma unroll
            for (int m=1;m<16;m<<=1){ sum += __shfl_xor(sum,m,64); sq += __shfl_xor(sq,m,64); }
            float mu = sum*(1.0f/128.0f);
            float rs = rsqrtf(sq*(1.0f/128.0f)-mu*mu + EPS_LN);
            float o0[4], o1[4];
            #pragma unroll
            for (int i=0;i<4;i++){
                int c0 = l*4+i, c1 = 64+l*4+i;
                o0[i] = (sa.f[i]-mu)*rs*e_ws[c0]+e_bs[c0];
                o1[i] = (sb.f[i]-mu)*rs*e_ws[c1]+e_bs[c1];
            }
            st_bf4(sAbC, g, 1152, 128+l*4, o0[0],o0[1],o0[2],o0[3]);
            st_bf4(sAbC, g, 1152, 192+l*4, o1[0],o1[1],o1[2],o1[3]);
        }
        {   // edge vector LN + rotate (u block 64..127)
            F4 va, vb, vc;
            va.v = *(const float4*)(ef + 128 + l*12);
            vb.v = *(const float4*)(ef + 128 + l*12 + 4);
            vc.v = *(const float4*)(ef + 128 + l*12 + 8);
            float vv[12];
            #pragma unroll
            for (int i=0;i<4;i++){ vv[i]=va.f[i]; vv[4+i]=vb.f[i]; vv[8+i]=vc.f[i]; }
            float sq=0.f;
            #pragma unroll
            for (int i=0;i<12;i++) sq += vv[i]*vv[i];
            #pragma unroll
            for (int m=1;m<16;m<<=1) sq += __shfl_xor(sq,m,64);
            float rv = rsqrtf(sq*(1.0f/192.0f) + EPS_LN);
            float f0[4], f1[4], f2[4];
            #pragma unroll
            for (int j=0;j<4;j++){
                int u = 4*l + j;
                float sc = rv * e_wv[u];
                float x = vv[3*j]*sc, y = vv[3*j+1]*sc, z = vv[3*j+2]*sc;
                f0[j] = ax*x+ay*y+az*z;
                f1[j] = bx*x+by*y+bz*z;
                f2[j] = cx*x+cy*y+cz*z;
            }
            st_bf4(sAbC, g, 1152, 384+64+4*l, f0[0],f0[1],f0[2],f0[3]);
            st_bf4(sVFC, g, 384, 64+4*l, f1[0],f1[1],f1[2],f1[3]);
            st_bf4(sVFC+6144, g, 384, 64+4*l, f2[0],f2[1],f2[2],f2[3]);
        }
        {   // nv[ctr] gather + rotate (u block 0..63)
            const float* pv = nv + (size_t)ct*192 + l*12;
            F4 va, vb, vc;
            va.v = *(const float4*)(pv);
            vb.v = *(const float4*)(pv+4);
            vc.v = *(const float4*)(pv+8);
            float vv[12];
            #pragma unroll
            for (int i=0;i<4;i++){ vv[i]=va.f[i]; vv[4+i]=vb.f[i]; vv[8+i]=vc.f[i]; }
            float f0[4], f1[4], f2[4];
            #pragma unroll
            for (int j=0;j<4;j++){
                float x = vv[3*j], y = vv[3*j+1], z = vv[3*j+2];
                f0[j] = ax*x+ay*y+az*z;
                f1[j] = bx*x+by*y+bz*z;
                f2[j] = cx*x+cy*y+cz*z;
            }
            st_bf4(sAbC, g, 1152, 384+4*l, f0[0],f0[1],f0[2],f0[3]);
            st_bf4(sVFC, g, 384, 4*l, f1[0],f1[1],f1[2],f1[3]);
            st_bf4(sVFC+6144, g, 384, 4*l, f2[0],f2[1],f2[2],f2[3]);
        }
        {   // nv[nbr] gather + rotate (u block 128..191)
            const float* pv = nv + (size_t)nb*192 + l*12;
            F4 va, vb, vc;
            va.v = *(const float4*)(pv);
            vb.v = *(const float4*)(pv+4);
            vc.v = *(const float4*)(pv+8);
            float vv[12];
            #pragma unroll
            for (int i=0;i<4;i++){ vv[i]=va.f[i]; vv[4+i]=vb.f[i]; vv[8+i]=vc.f[i]; }
            float f0[4], f1[4], f2[4];
            #pragma unroll
            for (int j=0;j<4;j++){
                float x = vv[3*j], y = vv[3*j+1], z = vv[3*j+2];
                f0[j] = ax*x+ay*y+az*z;
                f1[j] = bx*x+by*y+bz*z;
                f2[j] = cx*x+cy*y+cz*z;
            }
            st_bf4(sAbC, g, 1152, 384+128+4*l, f0[0],f0[1],f0[2],f0[3]);
            st_bf4(sVFC, g, 384, 128+4*l, f1[0],f1[1],f1[2],f1[3]);
            st_bf4(sVFC+6144, g, 384, 128+4*l, f2[0],f2[1],f2[2],f2[3]);
        }
    }
    __syncthreads();

    // ---- MFMA phase ----
    const int w  = t >> 6;        // wave id
    const int ln = t & 63;
    const int cc = ln & 15;       // row (A) / col (B,C) index
    const int gq = ln >> 4;       // k-group

    f32x4 accM[4] = {{0,0,0,0},{0,0,0,0},{0,0,0,0},{0,0,0,0}};
    // main GEMM: C[16e][256] = A[16e][576] x W[576][256]; wave w owns cols [64w,64w+64)
    {
        const __bf16* wb0 = Wt + (size_t)(64*w + 0  + cc)*576;
        const __bf16* wb1 = Wt + (size_t)(64*w + 16 + cc)*576;
        const __bf16* wb2 = Wt + (size_t)(64*w + 32 + cc)*576;
        const __bf16* wb3 = Wt + (size_t)(64*w + 48 + cc)*576;
        for (int ks=0; ks<18; ks++){
            bf16x8 a = ld_frag(sAbC, cc, 1152, ks*64 + 16*gq);
            int ko = ks*32 + 8*gq;
            bf16x8 b0 = *(const bf16x8*)(wb0 + ko);
            bf16x8 b1 = *(const bf16x8*)(wb1 + ko);
            bf16x8 b2 = *(const bf16x8*)(wb2 + ko);
            bf16x8 b3 = *(const bf16x8*)(wb3 + ko);
            accM[0] = __builtin_amdgcn_mfma_f32_16x16x32_bf16(a, b0, accM[0], 0,0,0);
            accM[1] = __builtin_amdgcn_mfma_f32_16x16x32_bf16(a, b1, accM[1], 0,0,0);
            accM[2] = __builtin_amdgcn_mfma_f32_16x16x32_bf16(a, b2, accM[2], 0,0,0);
            accM[3] = __builtin_amdgcn_mfma_f32_16x16x32_bf16(a, b3, accM[3], 0,0,0);
        }
    }
    // vp/vm GEMMs: wave w owns u-cols [16w,16w+16)
    f32x4 aP1={0,0,0,0}, aP2={0,0,0,0}, aM1={0,0,0,0}, aM2={0,0,0,0};
    {
        const __bf16* wr = w1rt + (size_t)(16*w + cc)*192;
        const __bf16* wi = w1it + (size_t)(16*w + cc)*192;
        for (int ks=0; ks<6; ks++){
            bf16x8 a1 = ld_frag(sVFC,        cc, 384, ks*64 + 16*gq);
            bf16x8 a2 = ld_frag(sVFC + 6144, cc, 384, ks*64 + 16*gq);
            int ko = ks*32 + 8*gq;
            bf16x8 br = *(const bf16x8*)(wr + ko);
            bf16x8 bi = *(const bf16x8*)(wi + ko);
            aP1 = __builtin_amdgcn_mfma_f32_16x16x32_bf16(a1, br, aP1, 0,0,0);
            aP2 = __builtin_amdgcn_mfma_f32_16x16x32_bf16(a2, bi, aP2, 0,0,0);
            aM1 = __builtin_amdgcn_mfma_f32_16x16x32_bf16(a1, bi, aM1, 0,0,0);
            aM2 = __builtin_amdgcn_mfma_f32_16x16x32_bf16(a2, br, aM2, 0,0,0);
        }
    }
    __syncthreads();   // all LDS reads of sAb/sVF done; safe to overlay sO

    // spill main accs to sO (f32), scaled
    {
        const float rn0 = 0.0416666666667f;   // 1/sqrt(576)
        #pragma unroll
        for (int jt=0;jt<4;jt++){
            #pragma unroll
            for (int j=0;j<4;j++){
                sO[(gq*4+j)*260 + 64*w + 16*jt + cc] = accM[jt][j]*rn0;
            }
        }
    }
    float vp[4], vm[4];
    {
        const float n1 = 0.0721687836487f;    // 1/sqrt(192)
        #pragma unroll
        for (int j=0;j<4;j++){ vp[j] = (aP1[j]-aP2[j])*n1; vm[j] = (aM1[j]+aM2[j])*n1; }
    }
    __syncthreads();

    // ---- E0: silu in place, gate+rotate (lane layout), env weights ----
    {   // gate + rotate back (R^T) -> MV  [lane layout: 4 edges x 1 u per lane]
        int u = w*16 + cc;
        #pragma unroll
        for (int j=0;j<4;j++){
            int er = gq*4 + j;
            if (blockIdx.x*16 + er < EA){
                const float* Rr = &sR[er*12];
                float s0 = sO[er*260 + 192 + u];
                float gt = sigmoidf_(sO[er*260 + 128 + u]);
                float p = vp[j], q = vm[j];
                float4 o;
                o.x = gt*(Rr[0]*s0 + Rr[3]*p + Rr[6]*q);
                o.y = gt*(Rr[1]*s0 + Rr[4]*p + Rr[7]*q);
                o.z = gt*(Rr[2]*s0 + Rr[5]*p + Rr[8]*q);
                o.w = 0.0f;
                *(float4*)&MV[er*260 + u*4] = o;
            }
        }
    }
    if (act) {
        {   // silu of scalar part, in place on sO[:, :128]
            int i0 = l*8;
            F4 oa, ob;
            oa.v = *(const float4*)&sO[g*260 + i0];
            ob.v = *(const float4*)&sO[g*260 + i0 + 4];
            #pragma unroll
            for (int i=0;i<4;i++){ oa.f[i] = siluf_(oa.f[i]); ob.f[i] = siluf_(ob.f[i]); }
            *(float4*)&sO[g*260 + i0]     = oa.v;
            *(float4*)&sO[g*260 + i0 + 4] = ob.v;
        }
        {   // env weights: w = latents[ae] @ env_w / sqrt(128)
            const int cc2 = l*12;
            float wacc[12];
            #pragma unroll
            for (int i=0;i<12;i++) wacc[i]=0.f;
            const float* lat = latents + (size_t)ae*128;
            for (int k=0;k<128;k+=4){
                F4 la;
                la.v = *(const float4*)(lat + k);
                #pragma unroll
                for (int kk=0;kk<4;kk++){
                    const float* er_ = env_w + (size_t)(k+kk)*192 + cc2;
                    F4 e0,e1,e2;
                    e0.v = *(const float4*)(er_);
                    e1.v = *(const float4*)(er_+4);
                    e2.v = *(const float4*)(er_+8);
                    #pragma unroll
                    for (int i=0;i<4;i++){
                        wacc[i]   += la.f[kk]*e0.f[i];
                        wacc[4+i] += la.f[kk]*e1.f[i];
                        wacc[8+i] += la.f[kk]*e2.f[i];
                    }
                }
            }
            const float inv128 = 0.0883883476483f;   // 1/sqrt(128)
            #pragma unroll
            for (int i=0;i<12;i++) WE[g*196 + cc2 + i] = wacc[i]*inv128;
        }
    }
    __syncthreads();

    // ---- E2: lp linears + env scaling + atomic scatter ----
    if (act) {
        const float inv_avg = 0.288675134595f;   // 1/sqrt(12)
        {   // scalar path: ms1 = silu(ms)@lp_ws/sqrt(128) + lp_bs, * w, scatter
            int c0 = l*8;
            float a8[8];
            #pragma unroll
            for (int i=0;i<8;i++) a8[i]=0.f;
            for (int k=0;k<128;k+=4){
                F4 av;
                av.v = *(const float4*)&sO[g*260 + k];
                #pragma unroll
                for (int kk=0;kk<4;kk++){
                    const float* wr = lp_ws + (size_t)(k+kk)*128 + c0;
                    F4 w0, w1_;
                    w0.v  = *(const float4*)(wr);
                    w1_.v = *(const float4*)(wr+4);
                    #pragma unroll
                    for (int i=0;i<4;i++){ a8[i] += av.f[kk]*w0.f[i]; a8[4+i] += av.f[kk]*w1_.f[i]; }
                }
            }
            const float s128 = 0.0883883476483f;
            #pragma unroll
            for (int i=0;i<8;i++){
                int c = c0+i;
                float val = (a8[i]*s128 + lp_bs[c]) * WE[g*196 + c] * inv_avg;
                atomicAdd(&agg_s[(size_t)ct*128 + c], val);
            }
        }
        {   // vector path: mv1[k][m] = sum_u mv[u][m]*lp_wv[u][k]/8, * w, scatter
            int k0 = l*4;
            float av[4][3];
            #pragma unroll
            for (int j=0;j<4;j++)
                #pragma unroll
                for (int m2=0;m2<3;m2++) av[j][m2]=0.f;
            for (int u=0;u<64;u++){
                F4 wv4, mv4;
                wv4.v = *(const float4*)(lp_wv + (size_t)u*64 + k0);
                mv4.v = *(const float4*)&MV[g*260 + u*4];
                #pragma unroll
                for (int j=0;j<4;j++){
                    av[j][0] += wv4.f[j]*mv4.f[0];
                    av[j][1] += wv4.f[j]*mv4.f[1];
                    av[j][2] += wv4.f[j]*mv4.f[2];
                }
            }
            #pragma unroll
            for (int j=0;j<4;j++){
                int k = k0+j;
                float wk = WE[g*196 + 128 + k] * 0.125f * inv_avg;
                #pragma unroll
                for (int m2=0;m2<3;m2++)
                    atomicAdd(&agg_v[(size_t)ct*192 + k*3 + m2], av[j][m2]*wk);
            }
        }
    }
}

// ---------------- Kernel C: per-node onehot path + output ----------------
__global__ void node_out_kernel(
    const float* __restrict__ nf,
    const int* __restrict__ atom_type,
    const float* __restrict__ agg_s, const float* __restrict__ agg_v,
    const float* __restrict__ oh_ss, const float* __restrict__ oh_sg, const float* __restrict__ oh_vv,
    const float* __restrict__ ohl_ws, const float* __restrict__ ohl_bs, const float* __restrict__ ohl_wv,
    const float* __restrict__ res_param,
    float* __restrict__ out, int N)
{
    __shared__ float AGS[128];
    __shared__ float AGV[192];
    __shared__ float TSs[128];
    __shared__ float SG[64];
    __shared__ float TV[192];
    const int n = blockIdx.x;
    const int t = threadIdx.x;
    const int at = atom_type[n];
    if (t < 128) AGS[t] = agg_s[(size_t)n*128 + t];
    if (t < 192) AGV[t] = agg_v[(size_t)n*192 + t];
    __syncthreads();
    const float n_ss = 0.0110485434560f;   // 1/sqrt(128*64)
    const float n_vv = 0.015625f;          // 1/sqrt(64*64)
    if (t < 128) {
        float acc = 0.0f;
        for (int u=0;u<128;u++) acc += AGS[u]*oh_ss[(size_t)u*8192 + (size_t)at*128 + t];
        TSs[t] = siluf_(acc*n_ss);
    } else if (t < 192) {
        int k = t-128;
        float acc = 0.0f;
        for (int u=0;u<128;u++) acc += AGS[u]*oh_sg[(size_t)u*4096 + (size_t)at*64 + k];
        SG[k] = sigmoidf_(acc*n_ss);
    } else {
        int k = t-192;
        float a0=0,a1=0,a2=0;
        for (int u=0;u<64;u++){
            float w = oh_vv[(size_t)u*4096 + (size_t)at*64 + k];
            a0 += AGV[u*3+0]*w;
            a1 += AGV[u*3+1]*w;
            a2 += AGV[u*3+2]*w;
        }
        TV[k*3+0]=a0*n_vv; TV[k*3+1]=a1*n_vv; TV[k*3+2]=a2*n_vv;
    }
    __syncthreads();
    const float alpha = sigmoidf_(res_param[0]);
    const float beta  = 1.0f - alpha;
    if (t < 128) {
        float acc = 0.0f;
        for (int k=0;k<128;k++) acc += TSs[k]*ohl_ws[(size_t)k*128 + t];
        float val = acc*0.0883883476483f + ohl_bs[t];
        out[(size_t)n*320 + t] = alpha*nf[(size_t)n*320 + t] + beta*val;
    } else if (t >= 192) {
        int k = t-192;
        float a0=0,a1=0,a2=0;
        for (int u=0;u<64;u++){
            float w = ohl_wv[(size_t)u*64 + k]*SG[u];
            a0 += TV[u*3+0]*w; a1 += TV[u*3+1]*w; a2 += TV[u*3+2]*w;
        }
        size_t base = (size_t)n*320 + 128 + (size_t)k*3;
        out[base+0] = alpha*nf[base+0] + beta*(a0*0.125f);
        out[base+1] = alpha*nf[base+1] + beta*(a1*0.125f);
        out[base+2] = alpha*nf[base+2] + beta*(a2*0.125f);
    }
}

extern "C" void kernel_launch(void* const* d_in, const int* in_sizes, int n_in,
                              void* d_out, int out_size, void* d_ws, size_t ws_size,
                              hipStream_t stream)
{
    const float* latents       = (const float*)d_in[0];
    const float* node_features = (const float*)d_in[1];
    const float* edge_features = (const float*)d_in[2];
    const int*   atom_type     = (const int*)d_in[3];
    // d_in[4] node_onehot unused
    const int*   edge_index    = (const int*)d_in[5];
    const float* edge_vector   = (const float*)d_in[6];
    const int*   active_edges  = (const int*)d_in[7];
    const float* sln_n_ws = (const float*)d_in[8];
    const float* sln_n_bs = (const float*)d_in[9];
    const float* sln_n_wv = (const float*)d_in[10];
    const float* sln_e_ws = (const float*)d_in[11];
    const float* sln_e_bs = (const float*)d_in[12];
    const float* sln_e_wv = (const float*)d_in[13];
    const float* so2_w0   = (const float*)d_in[14];
    const float* so2_w1r  = (const float*)d_in[15];
    const float* so2_w1i  = (const float*)d_in[16];
    const float* env_w    = (const float*)d_in[17];
    const float* lp_ws    = (const float*)d_in[18];
    const float* lp_bs    = (const float*)d_in[19];
    const float* lp_wv    = (const float*)d_in[20];
    const float* oh_w_ss  = (const float*)d_in[21];
    const float* oh_w_sg  = (const float*)d_in[22];
    const float* oh_w_vv  = (const float*)d_in[23];
    const float* ohl_ws   = (const float*)d_in[24];
    const float* ohl_bs   = (const float*)d_in[25];
    const float* ohl_wv   = (const float*)d_in[26];
    const float* res_param= (const float*)d_in[27];
    float* out = (float*)d_out;

    const int N  = in_sizes[1] / 320;
    const int EF = in_sizes[5] / 2;
    const int EA = in_sizes[7];

    float* ns    = (float*)d_ws;
    float* nv    = ns + (size_t)N*128;
    float* agg_s = nv + (size_t)N*192;
    float* agg_v = agg_s + (size_t)N*128;
    __bf16* Wt   = (__bf16*)(agg_v + (size_t)N*192);
    __bf16* w1rt = Wt + 576*256;
    __bf16* w1it = w1rt + 64*192;

    hipMemsetAsync(agg_s, 0, (size_t)N*(128+192)*sizeof(float), stream);
    prep_weights<<<576, 256, 0, stream>>>(so2_w0, so2_w1r, so2_w1i, Wt, w1rt, w1it);
    node_ln_kernel<<<(N+3)/4, 256, 0, stream>>>(node_features, sln_n_ws, sln_n_bs, sln_n_wv, ns, nv, N);
    edge_kernel<<<(EA+15)/16, 256, 0, stream>>>(latents, edge_features, edge_index, edge_vector, active_edges,
        sln_e_ws, sln_e_bs, sln_e_wv, Wt, w1rt, w1it, env_w, lp_ws, lp_bs, lp_wv,
        ns, nv, agg_s, agg_v, EA, EF);
    node_out_kernel<<<N, 256, 0, stream>>>(node_features, atom_type, agg_s, agg_v, oh_w_ss, oh_w_sg, oh_w_vv,
        ohl_ws, ohl_bs, ohl_wv, res_param, out, N);
}

// Round 3
// 876.059 us; speedup vs baseline: 2.0035x; 1.6197x over previous
//
#include <hip/hip_runtime.h>

#define EPS_LN 1e-8f

typedef __bf16 bf16x8 __attribute__((ext_vector_type(8)));
typedef float  f32x4  __attribute__((ext_vector_type(4)));

__device__ __forceinline__ float sigmoidf_(float x){ return 1.0f/(1.0f+__expf(-x)); }
__device__ __forceinline__ float siluf_(float x){ return x*sigmoidf_(x); }
__device__ __forceinline__ unsigned short f2bf(float x){ union{ __bf16 b; unsigned short u;} c; c.b = (__bf16)x; return c.u; }
__device__ __forceinline__ float bf2f(unsigned short u){ return __uint_as_float(((unsigned)u)<<16); }

union F4 { float4 v; float f[4]; };

// swizzled bf16 store of 4 consecutive elements (k multiple of 4)
__device__ __forceinline__ void st_bf4(char* base, int row, int stride_bytes, int k,
                                       float x0, float x1, float x2, float x3){
    union { __bf16 h[4]; unsigned long long u; } p;
    p.h[0]=(__bf16)x0; p.h[1]=(__bf16)x1; p.h[2]=(__bf16)x2; p.h[3]=(__bf16)x3;
    *(unsigned long long*)(base + row*stride_bytes + ((2*k) ^ ((row&7)<<4))) = p.u;
}
// swizzled 16B fragment load (kbyte multiple of 16)
__device__ __forceinline__ bf16x8 ld_frag(const char* base, int row, int stride_bytes, int kbyte){
    return *(const bf16x8*)(base + row*stride_bytes + (kbyte ^ ((row&7)<<4)));
}

// ---------------- weight prep: transpose + f32->bf16 ----------------
__global__ void prep_weights(const float* __restrict__ w0,
                             const float* __restrict__ w1r, const float* __restrict__ w1i,
                             __bf16* __restrict__ Wt, __bf16* __restrict__ w1rt, __bf16* __restrict__ w1it)
{
    int t = blockIdx.x*256 + threadIdx.x;
    if (t < 576*256){
        int c = t/576, k = t%576;
        Wt[t] = (__bf16)w0[(size_t)k*256 + c];
    }
    if (t < 64*192){
        int c = t/192, k = t%192;
        w1rt[t] = (__bf16)w1r[(size_t)k*64 + c];
        w1it[t] = (__bf16)w1i[(size_t)k*64 + c];
    }
}

// ---------------- CSR build ----------------
__global__ void csr_count(const int* __restrict__ ei, const int* __restrict__ act,
                          int* __restrict__ cnt, int EA)
{
    int e = blockIdx.x*256 + threadIdx.x;
    if (e < EA) atomicAdd(&cnt[ei[act[e]]], 1);
}

__global__ void csr_scan(const int* __restrict__ cnt, int* __restrict__ offs,
                         int* __restrict__ cursor, int N)
{
    __shared__ int part[256];
    int t = threadIdx.x;
    int chunk = (N + 255) / 256;
    int lo = t*chunk, hi = lo+chunk; if (hi > N) hi = N; if (lo > N) lo = N;
    int s = 0;
    for (int i=lo;i<hi;i++) s += cnt[i];
    part[t] = s;
    __syncthreads();
    for (int d=1; d<256; d<<=1){
        int v = (t>=d) ? part[t-d] : 0;
        __syncthreads();
        part[t] += v;
        __syncthreads();
    }
    int run = (t==0) ? 0 : part[t-1];
    for (int i=lo;i<hi;i++){
        offs[i] = run; cursor[i] = run;
        run += cnt[i];
    }
    if (t==255) offs[N] = part[255];
}

__global__ void csr_fill(const int* __restrict__ ei, const int* __restrict__ act,
                         int* __restrict__ cursor, int* __restrict__ elist, int EA)
{
    int e = blockIdx.x*256 + threadIdx.x;
    if (e < EA){
        int n = ei[act[e]];
        int p = atomicAdd(&cursor[n], 1);
        elist[p] = e;
    }
}

// ---------------- Kernel A: node separable layernorm (one wave per node) ----------------
__global__ void node_ln_kernel(const float* __restrict__ nf,
                               const float* __restrict__ ws, const float* __restrict__ bs,
                               const float* __restrict__ wv,
                               float* __restrict__ ns, float* __restrict__ nv, int N)
{
    int t = threadIdx.x;
    int lane = t & 63;
    int n = blockIdx.x*4 + (t>>6);
    if (n >= N) return;
    const float* row = nf + (size_t)n*320;
    float s0 = row[lane], s1 = row[64+lane];
    float sum = s0+s1, sq = s0*s0+s1*s1;
    #pragma unroll
    for (int m=1;m<64;m<<=1){ sum += __shfl_xor(sum,m,64); sq += __shfl_xor(sq,m,64); }
    float mu = sum*(1.0f/128.0f);
    float rs = rsqrtf(sq*(1.0f/128.0f) - mu*mu + EPS_LN);
    ns[(size_t)n*128+lane]    = (s0-mu)*rs*ws[lane]    + bs[lane];
    ns[(size_t)n*128+64+lane] = (s1-mu)*rs*ws[64+lane] + bs[64+lane];
    float v0 = row[128+lane], v1 = row[192+lane], v2 = row[256+lane];
    float vs = v0*v0+v1*v1+v2*v2;
    #pragma unroll
    for (int m=1;m<64;m<<=1) vs += __shfl_xor(vs,m,64);
    float rv = rsqrtf(vs*(1.0f/192.0f) + EPS_LN);
    nv[(size_t)n*192+lane]     = v0*rv*wv[lane/3];
    nv[(size_t)n*192+64+lane]  = v1*rv*wv[(64+lane)/3];
    nv[(size_t)n*192+128+lane] = v2*rv*wv[(128+lane)/3];
}

// ---------------- Kernel B: fused edge kernel (MFMA main + vp/vm GEMMs) ----------------
// 16 edges/block, 256 threads (4 waves). Writes per-edge bf16 message row [320]:
//   [0..128) scalar (lp+env+inv_avg applied), [128..320) vector k*3+m layout.
__launch_bounds__(256, 3)
__global__ void edge_kernel(
    const float* __restrict__ latents,
    const float* __restrict__ ef_all,
    const int*   __restrict__ edge_index,
    const float* __restrict__ edge_vector,
    const int*   __restrict__ active_edges,
    const float* __restrict__ e_ws, const float* __restrict__ e_bs, const float* __restrict__ e_wv,
    const __bf16* __restrict__ Wt,      // [256][576] bf16 (transposed so2_w0)
    const __bf16* __restrict__ w1rt,    // [64][192]
    const __bf16* __restrict__ w1it,    // [64][192]
    const float* __restrict__ env_w,
    const float* __restrict__ lp_ws, const float* __restrict__ lp_bs, const float* __restrict__ lp_wv,
    const float* __restrict__ ns, const float* __restrict__ nv,
    unsigned short* __restrict__ eout,
    int EA, int EF)
{
    __shared__ __align__(16) char smem[46592];
    char* sAbC = smem;                    // 16*1152 = 18432
    char* sVFC = smem + 18432;            // 2*16*384 = 12288 (ends 30720)
    float* sO  = (float*)smem;            // 16*260*4 = 16640
    float* MV  = (float*)(smem + 16640);  // 16*260*4 = 16640 (ends 33280)
    float* WE  = (float*)(smem + 33280);  // 16*196*4 = 12544 (ends 45824)
    float* sR  = (float*)(smem + 45824);  // 16*12*4  = 768   (ends 46592)

    const int t = threadIdx.x;
    const int g = t >> 4, l = t & 15;
    const int e = blockIdx.x*16 + g;
    const bool act = (e < EA);

    int ct = 0, ae = 0;

    // ---- staging phase ----
    if (act) {
        ae = active_edges[e];
        ct = edge_index[ae];
        int nb = edge_index[EF + ae];
        (void)ct;
        // frame from edge_vector
        float ex = edge_vector[(size_t)ae*3+0];
        float ey = edge_vector[(size_t)ae*3+1];
        float ez = edge_vector[(size_t)ae*3+2];
        float rn = rsqrtf(ex*ex+ey*ey+ez*ez + EPS_LN);
        float ax = ex*rn, ay = ey*rn, az = ez*rn;
        float rx, ry;
        if (fabsf(ax) < 0.9f) { rx = 1.0f; ry = 0.0f; } else { rx = 0.0f; ry = 1.0f; }
        float bx = -az*ry, by = az*rx, bz = ax*ry - ay*rx;
        float bn = rsqrtf(bx*bx+by*by+bz*bz + EPS_LN);
        bx*=bn; by*=bn; bz*=bn;
        float cx = ay*bz - az*by;
        float cy = az*bx - ax*bz;
        float cz = ax*by - ay*bx;
        if (l == 0){
            float* Rr = &sR[g*12];
            Rr[0]=ax; Rr[1]=ay; Rr[2]=az;
            Rr[3]=bx; Rr[4]=by; Rr[5]=bz;
            Rr[6]=cx; Rr[7]=cy; Rr[8]=cz;
        }

        {   // gather layernormed node scalars -> bf16 A tile
            const float4* pc4 = (const float4*)(ns + (size_t)ct*128);
            const float4* pn4 = (const float4*)(ns + (size_t)nb*128);
            F4 a,b2,c,d;
            a.v = pc4[l]; b2.v = pc4[16+l]; c.v = pn4[l]; d.v = pn4[16+l];
            st_bf4(sAbC, g, 1152, l*4,       a.f[0],a.f[1],a.f[2],a.f[3]);
            st_bf4(sAbC, g, 1152, 64+l*4,    b2.f[0],b2.f[1],b2.f[2],b2.f[3]);
            st_bf4(sAbC, g, 1152, 256+l*4,   c.f[0],c.f[1],c.f[2],c.f[3]);
            st_bf4(sAbC, g, 1152, 320+l*4,   d.f[0],d.f[1],d.f[2],d.f[3]);
        }
        const float* ef = ef_all + (size_t)e*320;
        {   // edge scalar LN
            F4 sa, sb;
            sa.v = *(const float4*)(ef + l*4);
            sb.v = *(const float4*)(ef + 64 + l*4);
            float sum=0.f, sq=0.f;
            #pragma unroll
            for (int i=0;i<4;i++){ sum += sa.f[i]+sb.f[i]; sq += sa.f[i]*sa.f[i]+sb.f[i]*sb.f[i]; }
            #pragma unroll
            for (int m=1;m<16;m<<=1){ sum += __shfl_xor(sum,m,64); sq += __shfl_xor(sq,m,64); }
            float mu = sum*(1.0f/128.0f);
            float rs = rsqrtf(sq*(1.0f/128.0f)-mu*mu + EPS_LN);
            float o0[4], o1[4];
            #pragma unroll
            for (int i=0;i<4;i++){
                int c0 = l*4+i, c1 = 64+l*4+i;
                o0[i] = (sa.f[i]-mu)*rs*e_ws[c0]+e_bs[c0];
                o1[i] = (sb.f[i]-mu)*rs*e_ws[c1]+e_bs[c1];
            }
            st_bf4(sAbC, g, 1152, 128+l*4, o0[0],o0[1],o0[2],o0[3]);
            st_bf4(sAbC, g, 1152, 192+l*4, o1[0],o1[1],o1[2],o1[3]);
        }
        {   // edge vector LN + rotate (u block 64..127)
            F4 va, vb, vc;
            va.v = *(const float4*)(ef + 128 + l*12);
            vb.v = *(const float4*)(ef + 128 + l*12 + 4);
            vc.v = *(const float4*)(ef + 128 + l*12 + 8);
            float vv[12];
            #pragma unroll
            for (int i=0;i<4;i++){ vv[i]=va.f[i]; vv[4+i]=vb.f[i]; vv[8+i]=vc.f[i]; }
            float sq=0.f;
            #pragma unroll
            for (int i=0;i<12;i++) sq += vv[i]*vv[i];
            #pragma unroll
            for (int m=1;m<16;m<<=1) sq += __shfl_xor(sq,m,64);
            float rv = rsqrtf(sq*(1.0f/192.0f) + EPS_LN);
            float f0[4], f1[4], f2[4];
            #pragma unroll
            for (int j=0;j<4;j++){
                int u = 4*l + j;
                float sc = rv * e_wv[u];
                float x = vv[3*j]*sc, y = vv[3*j+1]*sc, z = vv[3*j+2]*sc;
                f0[j] = ax*x+ay*y+az*z;
                f1[j] = bx*x+by*y+bz*z;
                f2[j] = cx*x+cy*y+cz*z;
            }
            st_bf4(sAbC, g, 1152, 384+64+4*l, f0[0],f0[1],f0[2],f0[3]);
            st_bf4(sVFC, g, 384, 64+4*l, f1[0],f1[1],f1[2],f1[3]);
            st_bf4(sVFC+6144, g, 384, 64+4*l, f2[0],f2[1],f2[2],f2[3]);
        }
        {   // nv[ctr] gather + rotate (u block 0..63)
            const float* pv = nv + (size_t)ct*192 + l*12;
            F4 va, vb, vc;
            va.v = *(const float4*)(pv);
            vb.v = *(const float4*)(pv+4);
            vc.v = *(const float4*)(pv+8);
            float vv[12];
            #pragma unroll
            for (int i=0;i<4;i++){ vv[i]=va.f[i]; vv[4+i]=vb.f[i]; vv[8+i]=vc.f[i]; }
            float f0[4], f1[4], f2[4];
            #pragma unroll
            for (int j=0;j<4;j++){
                float x = vv[3*j], y = vv[3*j+1], z = vv[3*j+2];
                f0[j] = ax*x+ay*y+az*z;
                f1[j] = bx*x+by*y+bz*z;
                f2[j] = cx*x+cy*y+cz*z;
            }
            st_bf4(sAbC, g, 1152, 384+4*l, f0[0],f0[1],f0[2],f0[3]);
            st_bf4(sVFC, g, 384, 4*l, f1[0],f1[1],f1[2],f1[3]);
            st_bf4(sVFC+6144, g, 384, 4*l, f2[0],f2[1],f2[2],f2[3]);
        }
        {   // nv[nbr] gather + rotate (u block 128..191)
            const float* pv = nv + (size_t)nb*192 + l*12;
            F4 va, vb, vc;
            va.v = *(const float4*)(pv);
            vb.v = *(const float4*)(pv+4);
            vc.v = *(const float4*)(pv+8);
            float vv[12];
            #pragma unroll
            for (int i=0;i<4;i++){ vv[i]=va.f[i]; vv[4+i]=vb.f[i]; vv[8+i]=vc.f[i]; }
            float f0[4], f1[4], f2[4];
            #pragma unroll
            for (int j=0;j<4;j++){
                float x = vv[3*j], y = vv[3*j+1], z = vv[3*j+2];
                f0[j] = ax*x+ay*y+az*z;
                f1[j] = bx*x+by*y+bz*z;
                f2[j] = cx*x+cy*y+cz*z;
            }
            st_bf4(sAbC, g, 1152, 384+128+4*l, f0[0],f0[1],f0[2],f0[3]);
            st_bf4(sVFC, g, 384, 128+4*l, f1[0],f1[1],f1[2],f1[3]);
            st_bf4(sVFC+6144, g, 384, 128+4*l, f2[0],f2[1],f2[2],f2[3]);
        }
    }
    __syncthreads();

    // ---- MFMA phase ----
    const int w  = t >> 6;        // wave id
    const int ln = t & 63;
    const int cc = ln & 15;       // row (A) / col (B,C) index
    const int gq = ln >> 4;       // k-group

    f32x4 accM[4] = {{0,0,0,0},{0,0,0,0},{0,0,0,0},{0,0,0,0}};
    // main GEMM: C[16e][256] = A[16e][576] x W[576][256]; wave w owns cols [64w,64w+64)
    {
        const __bf16* wb0 = Wt + (size_t)(64*w + 0  + cc)*576;
        const __bf16* wb1 = Wt + (size_t)(64*w + 16 + cc)*576;
        const __bf16* wb2 = Wt + (size_t)(64*w + 32 + cc)*576;
        const __bf16* wb3 = Wt + (size_t)(64*w + 48 + cc)*576;
        for (int ks=0; ks<18; ks++){
            bf16x8 a = ld_frag(sAbC, cc, 1152, ks*64 + 16*gq);
            int ko = ks*32 + 8*gq;
            bf16x8 b0 = *(const bf16x8*)(wb0 + ko);
            bf16x8 b1 = *(const bf16x8*)(wb1 + ko);
            bf16x8 b2 = *(const bf16x8*)(wb2 + ko);
            bf16x8 b3 = *(const bf16x8*)(wb3 + ko);
            accM[0] = __builtin_amdgcn_mfma_f32_16x16x32_bf16(a, b0, accM[0], 0,0,0);
            accM[1] = __builtin_amdgcn_mfma_f32_16x16x32_bf16(a, b1, accM[1], 0,0,0);
            accM[2] = __builtin_amdgcn_mfma_f32_16x16x32_bf16(a, b2, accM[2], 0,0,0);
            accM[3] = __builtin_amdgcn_mfma_f32_16x16x32_bf16(a, b3, accM[3], 0,0,0);
        }
    }
    // vp/vm GEMMs: wave w owns u-cols [16w,16w+16)
    f32x4 aP1={0,0,0,0}, aP2={0,0,0,0}, aM1={0,0,0,0}, aM2={0,0,0,0};
    {
        const __bf16* wr = w1rt + (size_t)(16*w + cc)*192;
        const __bf16* wi = w1it + (size_t)(16*w + cc)*192;
        for (int ks=0; ks<6; ks++){
            bf16x8 a1 = ld_frag(sVFC,        cc, 384, ks*64 + 16*gq);
            bf16x8 a2 = ld_frag(sVFC + 6144, cc, 384, ks*64 + 16*gq);
            int ko = ks*32 + 8*gq;
            bf16x8 br = *(const bf16x8*)(wr + ko);
            bf16x8 bi = *(const bf16x8*)(wi + ko);
            aP1 = __builtin_amdgcn_mfma_f32_16x16x32_bf16(a1, br, aP1, 0,0,0);
            aP2 = __builtin_amdgcn_mfma_f32_16x16x32_bf16(a2, bi, aP2, 0,0,0);
            aM1 = __builtin_amdgcn_mfma_f32_16x16x32_bf16(a1, bi, aM1, 0,0,0);
            aM2 = __builtin_amdgcn_mfma_f32_16x16x32_bf16(a2, br, aM2, 0,0,0);
        }
    }
    __syncthreads();   // all LDS reads of sAb/sVF done; safe to overlay sO

    // spill main accs to sO (f32), scaled
    {
        const float rn0 = 0.0416666666667f;   // 1/sqrt(576)
        #pragma unroll
        for (int jt=0;jt<4;jt++){
            #pragma unroll
            for (int j=0;j<4;j++){
                sO[(gq*4+j)*260 + 64*w + 16*jt + cc] = accM[jt][j]*rn0;
            }
        }
    }
    float vp[4], vm[4];
    {
        const float n1 = 0.0721687836487f;    // 1/sqrt(192)
        #pragma unroll
        for (int j=0;j<4;j++){ vp[j] = (aP1[j]-aP2[j])*n1; vm[j] = (aM1[j]+aM2[j])*n1; }
    }
    __syncthreads();

    // ---- E0: silu in place, gate+rotate (lane layout), env weights ----
    {   // gate + rotate back (R^T) -> MV  [lane layout: 4 edges x 1 u per lane]
        int u = w*16 + cc;
        #pragma unroll
        for (int j=0;j<4;j++){
            int er = gq*4 + j;
            if (blockIdx.x*16 + er < EA){
                const float* Rr = &sR[er*12];
                float s0 = sO[er*260 + 192 + u];
                float gt = sigmoidf_(sO[er*260 + 128 + u]);
                float p = vp[j], q = vm[j];
                float4 o;
                o.x = gt*(Rr[0]*s0 + Rr[3]*p + Rr[6]*q);
                o.y = gt*(Rr[1]*s0 + Rr[4]*p + Rr[7]*q);
                o.z = gt*(Rr[2]*s0 + Rr[5]*p + Rr[8]*q);
                o.w = 0.0f;
                *(float4*)&MV[er*260 + u*4] = o;
            }
        }
    }
    if (act) {
        {   // silu of scalar part, in place on sO[:, :128]
            int i0 = l*8;
            F4 oa, ob;
            oa.v = *(const float4*)&sO[g*260 + i0];
            ob.v = *(const float4*)&sO[g*260 + i0 + 4];
            #pragma unroll
            for (int i=0;i<4;i++){ oa.f[i] = siluf_(oa.f[i]); ob.f[i] = siluf_(ob.f[i]); }
            *(float4*)&sO[g*260 + i0]     = oa.v;
            *(float4*)&sO[g*260 + i0 + 4] = ob.v;
        }
        {   // env weights: w = latents[ae] @ env_w / sqrt(128)
            const int cc2 = l*12;
            float wacc[12];
            #pragma unroll
            for (int i=0;i<12;i++) wacc[i]=0.f;
            const float* lat = latents + (size_t)ae*128;
            for (int k=0;k<128;k+=4){
                F4 la;
                la.v = *(const float4*)(lat + k);
                #pragma unroll
                for (int kk=0;kk<4;kk++){
                    const float* er_ = env_w + (size_t)(k+kk)*192 + cc2;
                    F4 e0,e1,e2;
                    e0.v = *(const float4*)(er_);
                    e1.v = *(const float4*)(er_+4);
                    e2.v = *(const float4*)(er_+8);
                    #pragma unroll
                    for (int i=0;i<4;i++){
                        wacc[i]   += la.f[kk]*e0.f[i];
                        wacc[4+i] += la.f[kk]*e1.f[i];
                        wacc[8+i] += la.f[kk]*e2.f[i];
                    }
                }
            }
            const float inv128 = 0.0883883476483f;   // 1/sqrt(128)
            #pragma unroll
            for (int i=0;i<12;i++) WE[g*196 + cc2 + i] = wacc[i]*inv128;
        }
    }
    __syncthreads();

    // ---- E2: lp linears + env scaling + bf16 store of message row ----
    if (act) {
        const float inv_avg = 0.288675134595f;   // 1/sqrt(12)
        unsigned short* orow = eout + (size_t)e*320;
        {   // scalar path: ms1 = silu(ms)@lp_ws/sqrt(128) + lp_bs, * w
            int c0 = l*8;
            float a8[8];
            #pragma unroll
            for (int i=0;i<8;i++) a8[i]=0.f;
            for (int k=0;k<128;k+=4){
                F4 av;
                av.v = *(const float4*)&sO[g*260 + k];
                #pragma unroll
                for (int kk=0;kk<4;kk++){
                    const float* wr = lp_ws + (size_t)(k+kk)*128 + c0;
                    F4 w0, w1_;
                    w0.v  = *(const float4*)(wr);
                    w1_.v = *(const float4*)(wr+4);
                    #pragma unroll
                    for (int i=0;i<4;i++){ a8[i] += av.f[kk]*w0.f[i]; a8[4+i] += av.f[kk]*w1_.f[i]; }
                }
            }
            const float s128 = 0.0883883476483f;
            union { unsigned short h[8]; uint4 u; } ps;
            #pragma unroll
            for (int i=0;i<8;i++){
                int c = c0+i;
                ps.h[i] = f2bf((a8[i]*s128 + lp_bs[c]) * WE[g*196 + c] * inv_avg);
            }
            *(uint4*)(orow + c0) = ps.u;
        }
        {   // vector path: mv1[k][m] = sum_u mv[u][m]*lp_wv[u][k]/8, * w
            int k0 = l*4;
            float av[4][3];
            #pragma unroll
            for (int j=0;j<4;j++)
                #pragma unroll
                for (int m2=0;m2<3;m2++) av[j][m2]=0.f;
            for (int u=0;u<64;u++){
                F4 wv4, mv4;
                wv4.v = *(const float4*)(lp_wv + (size_t)u*64 + k0);
                mv4.v = *(const float4*)&MV[g*260 + u*4];
                #pragma unroll
                for (int j=0;j<4;j++){
                    av[j][0] += wv4.f[j]*mv4.f[0];
                    av[j][1] += wv4.f[j]*mv4.f[1];
                    av[j][2] += wv4.f[j]*mv4.f[2];
                }
            }
            union { unsigned short h[12]; uint2 u2[3]; } pv;
            #pragma unroll
            for (int j=0;j<4;j++){
                int k = k0+j;
                float wk = WE[g*196 + 128 + k] * 0.125f * inv_avg;
                #pragma unroll
                for (int m2=0;m2<3;m2++)
                    pv.h[j*3+m2] = f2bf(av[j][m2]*wk);
            }
            unsigned short* vb = orow + 128 + 12*l;
            *(uint2*)(vb)   = pv.u2[0];
            *(uint2*)(vb+4) = pv.u2[1];
            *(uint2*)(vb+8) = pv.u2[2];
        }
    }
}

// ---------------- Kernel C: per-node CSR aggregate + onehot path + output ----------------
__global__ void node_out_kernel(
    const float* __restrict__ nf,
    const int* __restrict__ atom_type,
    const int* __restrict__ offs, const int* __restrict__ elist,
    const unsigned short* __restrict__ eout,
    const float* __restrict__ oh_ss, const float* __restrict__ oh_sg, const float* __restrict__ oh_vv,
    const float* __restrict__ ohl_ws, const float* __restrict__ ohl_bs, const float* __restrict__ ohl_wv,
    const float* __restrict__ res_param,
    float* __restrict__ out, int N)
{
    __shared__ float AGS[128];
    __shared__ float AGV[192];
    __shared__ float TSs[128];
    __shared__ float SG[64];
    __shared__ float TV[192];
    const int n = blockIdx.x;
    const int t = threadIdx.x;
    const int at = atom_type[n];

    // CSR gather-aggregate: thread t owns col t, threads t<64 also col 256+t
    {
        int lo = offs[n], hi = offs[n+1];
        float a0 = 0.f, a1 = 0.f;
        for (int i=lo;i<hi;i++){
            const unsigned short* row = eout + (size_t)elist[i]*320;
            a0 += bf2f(row[t]);
            if (t < 64) a1 += bf2f(row[256+t]);
        }
        if (t < 128) AGS[t] = a0; else AGV[t-128] = a0;
        if (t < 64) AGV[128+t] = a1;
    }
    __syncthreads();
    const float n_ss = 0.0110485434560f;   // 1/sqrt(128*64)
    const float n_vv = 0.015625f;          // 1/sqrt(64*64)
    if (t < 128) {
        float acc = 0.0f;
        for (int u=0;u<128;u++) acc += AGS[u]*oh_ss[(size_t)u*8192 + (size_t)at*128 + t];
        TSs[t] = siluf_(acc*n_ss);
    } else if (t < 192) {
        int k = t-128;
        float acc = 0.0f;
        for (int u=0;u<128;u++) acc += AGS[u]*oh_sg[(size_t)u*4096 + (size_t)at*64 + k];
        SG[k] = sigmoidf_(acc*n_ss);
    } else {
        int k = t-192;
        float a0=0,a1=0,a2=0;
        for (int u=0;u<64;u++){
            float w = oh_vv[(size_t)u*4096 + (size_t)at*64 + k];
            a0 += AGV[u*3+0]*w;
            a1 += AGV[u*3+1]*w;
            a2 += AGV[u*3+2]*w;
        }
        TV[k*3+0]=a0*n_vv; TV[k*3+1]=a1*n_vv; TV[k*3+2]=a2*n_vv;
    }
    __syncthreads();
    const float alpha = sigmoidf_(res_param[0]);
    const float beta  = 1.0f - alpha;
    if (t < 128) {
        float acc = 0.0f;
        for (int k=0;k<128;k++) acc += TSs[k]*ohl_ws[(size_t)k*128 + t];
        float val = acc*0.0883883476483f + ohl_bs[t];
        out[(size_t)n*320 + t] = alpha*nf[(size_t)n*320 + t] + beta*val;
    } else if (t >= 192) {
        int k = t-192;
        float a0=0,a1=0,a2=0;
        for (int u=0;u<64;u++){
            float w = ohl_wv[(size_t)u*64 + k]*SG[u];
            a0 += TV[u*3+0]*w; a1 += TV[u*3+1]*w; a2 += TV[u*3+2]*w;
        }
        size_t base = (size_t)n*320 + 128 + (size_t)k*3;
        out[base+0] = alpha*nf[base+0] + beta*(a0*0.125f);
        out[base+1] = alpha*nf[base+1] + beta*(a1*0.125f);
        out[base+2] = alpha*nf[base+2] + beta*(a2*0.125f);
    }
}

extern "C" void kernel_launch(void* const* d_in, const int* in_sizes, int n_in,
                              void* d_out, int out_size, void* d_ws, size_t ws_size,
                              hipStream_t stream)
{
    const float* latents       = (const float*)d_in[0];
    const float* node_features = (const float*)d_in[1];
    const float* edge_features = (const float*)d_in[2];
    const int*   atom_type     = (const int*)d_in[3];
    // d_in[4] node_onehot unused
    const int*   edge_index    = (const int*)d_in[5];
    const float* edge_vector   = (const float*)d_in[6];
    const int*   active_edges  = (const int*)d_in[7];
    const float* sln_n_ws = (const float*)d_in[8];
    const float* sln_n_bs = (const float*)d_in[9];
    const float* sln_n_wv = (const float*)d_in[10];
    const float* sln_e_ws = (const float*)d_in[11];
    const float* sln_e_bs = (const float*)d_in[12];
    const float* sln_e_wv = (const float*)d_in[13];
    const float* so2_w0   = (const float*)d_in[14];
    const float* so2_w1r  = (const float*)d_in[15];
    const float* so2_w1i  = (const float*)d_in[16];
    const float* env_w    = (const float*)d_in[17];
    const float* lp_ws    = (const float*)d_in[18];
    const float* lp_bs    = (const float*)d_in[19];
    const float* lp_wv    = (const float*)d_in[20];
    const float* oh_w_ss  = (const float*)d_in[21];
    const float* oh_w_sg  = (const float*)d_in[22];
    const float* oh_w_vv  = (const float*)d_in[23];
    const float* ohl_ws   = (const float*)d_in[24];
    const float* ohl_bs   = (const float*)d_in[25];
    const float* ohl_wv   = (const float*)d_in[26];
    const float* res_param= (const float*)d_in[27];
    float* out = (float*)d_out;

    const int N  = in_sizes[1] / 320;
    const int EF = in_sizes[5] / 2;
    const int EA = in_sizes[7];

    // workspace layout
    float* ns    = (float*)d_ws;                         // N*128 f32
    float* nv    = ns + (size_t)N*128;                   // N*192 f32
    int*   cnt     = (int*)(nv + (size_t)N*192);         // N
    int*   offs    = cnt + N;                            // N+1
    int*   cursor  = offs + (N+1);                       // N
    int*   elist   = cursor + N;                         // EA
    __bf16* Wt   = (__bf16*)(elist + EA);                // 576*256
    __bf16* w1rt = Wt + 576*256;                         // 64*192
    __bf16* w1it = w1rt + 64*192;                        // 64*192
    unsigned short* eout = (unsigned short*)(w1it + 64*192);   // EA*320 bf16

    hipMemsetAsync(cnt, 0, (size_t)N*sizeof(int), stream);
    prep_weights<<<576, 256, 0, stream>>>(so2_w0, so2_w1r, so2_w1i, Wt, w1rt, w1it);
    node_ln_kernel<<<(N+3)/4, 256, 0, stream>>>(node_features, sln_n_ws, sln_n_bs, sln_n_wv, ns, nv, N);
    csr_count<<<(EA+255)/256, 256, 0, stream>>>(edge_index, active_edges, cnt, EA);
    csr_scan<<<1, 256, 0, stream>>>(cnt, offs, cursor, N);
    csr_fill<<<(EA+255)/256, 256, 0, stream>>>(edge_index, active_edges, cursor, elist, EA);
    edge_kernel<<<(EA+15)/16, 256, 0, stream>>>(latents, edge_features, edge_index, edge_vector, active_edges,
        sln_e_ws, sln_e_bs, sln_e_wv, Wt, w1rt, w1it, env_w, lp_ws, lp_bs, lp_wv,
        ns, nv, eout, EA, EF);
    node_out_kernel<<<N, 256, 0, stream>>>(node_features, atom_type, offs, elist, eout,
        oh_w_ss, oh_w_sg, oh_w_vv, ohl_ws, ohl_bs, ohl_wv, res_param, out, N);
}